// Round 3
// baseline (992.188 us; speedup 1.0000x reference)
//
#include <hip/hip_runtime.h>
#include <hip/hip_bf16.h>

#define L_ 2048
#define D_ 192
#define HK_ 48
#define EPS_ 1e-3f
#define SCALE_ 0.28867513459481287f  // 1/sqrt(12)

typedef __hip_bfloat16 bf16;

__device__ __forceinline__ float b2f(bf16 x) { return __bfloat162float(x); }
__device__ __forceinline__ bf16 f2b(float x) { return __float2bfloat16(x); }

// ---------------------------------------------------------------------------
// K1: LN1 + QKV projection. 16 rows/block, 256 threads.
// Phase A: 4 waves x 4 rows, per-wave shuffle LN -> xn in LDS.
// Phase B: threads 0..143 each own one output column (q/k/v x 48), 16 rows.
// ---------------------------------------------------------------------------
__global__ __launch_bounds__(256) void k_ln_qkv(
    const float* __restrict__ x, const float* __restrict__ g1, const float* __restrict__ b1,
    const float* __restrict__ wq, const float* __restrict__ bq,
    const float* __restrict__ wk, const float* __restrict__ bk,
    const float* __restrict__ wv, const float* __restrict__ bv,
    bf16* __restrict__ qo, bf16* __restrict__ ko, bf16* __restrict__ vo)
{
    __shared__ float xn[16 * D_];
    const int tid = threadIdx.x;
    const int wave = tid >> 6, lane = tid & 63;
    const int rowbase = blockIdx.x * 16;

    #pragma unroll
    for (int i = 0; i < 4; ++i) {
        const int r = wave * 4 + i;
        const float* xp = x + (size_t)(rowbase + r) * D_;
        const float x0 = xp[lane];
        const float x1 = xp[lane + 64];
        const float x2 = xp[lane + 128];
        float s = x0 + x1 + x2;
        float q = x0 * x0 + x1 * x1 + x2 * x2;
        #pragma unroll
        for (int m = 1; m < 64; m <<= 1) {
            s += __shfl_xor(s, m, 64);
            q += __shfl_xor(q, m, 64);
        }
        const float mean = s * (1.0f / 192.0f);
        const float var  = q * (1.0f / 192.0f) - mean * mean;
        const float rs   = rsqrtf(var + EPS_);
        xn[r * D_ + lane]       = (x0 - mean) * rs * g1[lane]       + b1[lane];
        xn[r * D_ + lane + 64]  = (x1 - mean) * rs * g1[lane + 64]  + b1[lane + 64];
        xn[r * D_ + lane + 128] = (x2 - mean) * rs * g1[lane + 128] + b1[lane + 128];
    }
    __syncthreads();

    if (tid < 144) {
        const int sel = tid / 48, col = tid % 48;
        const float* W  = sel == 0 ? wq : (sel == 1 ? wk : wv);
        const float* Bp = sel == 0 ? bq : (sel == 1 ? bk : bv);
        bf16* O         = sel == 0 ? qo : (sel == 1 ? ko : vo);
        float acc[16];
        #pragma unroll
        for (int r = 0; r < 16; ++r) acc[r] = 0.f;
        for (int c = 0; c < D_; c += 4) {
            const float w0 = W[(c + 0) * HK_ + col];
            const float w1 = W[(c + 1) * HK_ + col];
            const float w2 = W[(c + 2) * HK_ + col];
            const float w3 = W[(c + 3) * HK_ + col];
            #pragma unroll
            for (int r = 0; r < 16; ++r) {
                const float4 xv = *(const float4*)&xn[r * D_ + c];
                acc[r] = fmaf(xv.x, w0, fmaf(xv.y, w1, fmaf(xv.z, w2, fmaf(xv.w, w3, acc[r]))));
            }
        }
        const float bb = Bp[col];
        #pragma unroll
        for (int r = 0; r < 16; ++r)
            O[(size_t)(rowbase + r) * HK_ + col] = f2b(acc[r] + bb);
    }
}

// ---------------------------------------------------------------------------
// K2: causal attention. One block = one (b,h) x 256-query tile; 128 threads,
// 2 queries/thread. K/V staged 128 keys at a time into LDS (fp32).
// Fixed-max online softmax: scores bounded (|s| <~ 3), so p = exp(s - 8).
// ---------------------------------------------------------------------------
__global__ __launch_bounds__(128) void k_attn(
    const bf16* __restrict__ qb, const bf16* __restrict__ kb, const bf16* __restrict__ vb,
    bf16* __restrict__ ctx)
{
    __shared__ float Kl[128 * 12];
    __shared__ float Vl[128 * 12];
    const int tid  = threadIdx.x;
    const int bh   = blockIdx.x >> 3, tile = blockIdx.x & 7;
    const int b    = bh >> 2, h = bh & 3;
    const int q0   = tile * 256 + 2 * tid, q1 = q0 + 1;
    const size_t base = (size_t)b * L_ * HK_ + h * 12;

    float qr0[12], qr1[12], o0[12], o1[12];
    {
        const size_t qoff = base + (size_t)q0 * HK_;
        #pragma unroll
        for (int i = 0; i < 12; ++i) {
            qr0[i] = b2f(qb[qoff + i]);
            qr1[i] = b2f(qb[qoff + HK_ + i]);
            o0[i] = 0.f; o1[i] = 0.f;
        }
    }
    float l0 = 0.f, l1 = 0.f;
    const int nch = (tile + 1) * 2;
    for (int ch = 0; ch < nch; ++ch) {
        const int c0 = ch * 128;
        __syncthreads();
        {
            const size_t koff = base + (size_t)(c0 + tid) * HK_;
            #pragma unroll
            for (int i = 0; i < 12; ++i) Kl[tid * 12 + i] = b2f(kb[koff + i]);
            #pragma unroll
            for (int i = 0; i < 12; ++i) Vl[tid * 12 + i] = b2f(vb[koff + i]);
        }
        __syncthreads();
        for (int kk = 0; kk < 128; ++kk) {
            const int kidx = c0 + kk;
            float kr[12], vr[12];
            *(float4*)&kr[0] = *(const float4*)&Kl[kk * 12 + 0];
            *(float4*)&kr[4] = *(const float4*)&Kl[kk * 12 + 4];
            *(float4*)&kr[8] = *(const float4*)&Kl[kk * 12 + 8];
            float s0 = 0.f, s1 = 0.f;
            #pragma unroll
            for (int i = 0; i < 12; ++i) {
                s0 = fmaf(qr0[i], kr[i], s0);
                s1 = fmaf(qr1[i], kr[i], s1);
            }
            s0 *= SCALE_; s1 *= SCALE_;
            s0 = (kidx <= q0) ? s0 : -1e30f;
            s1 = (kidx <= q1) ? s1 : -1e30f;
            const float p0 = __expf(s0 - 8.0f);
            const float p1 = __expf(s1 - 8.0f);
            l0 += p0; l1 += p1;
            *(float4*)&vr[0] = *(const float4*)&Vl[kk * 12 + 0];
            *(float4*)&vr[4] = *(const float4*)&Vl[kk * 12 + 4];
            *(float4*)&vr[8] = *(const float4*)&Vl[kk * 12 + 8];
            #pragma unroll
            for (int i = 0; i < 12; ++i) {
                o0[i] = fmaf(p0, vr[i], o0[i]);
                o1[i] = fmaf(p1, vr[i], o1[i]);
            }
        }
    }
    const float inv0 = 1.0f / l0, inv1 = 1.0f / l1;
    const size_t ob = base + (size_t)q0 * HK_;
    #pragma unroll
    for (int i = 0; i < 12; ++i) {
        ctx[ob + i]       = f2b(o0[i] * inv0);
        ctx[ob + HK_ + i] = f2b(o1[i] * inv1);
    }
}

// ---------------------------------------------------------------------------
// K3: out-proj + residual + LN2. 8 rows/block, 192 threads (thread = channel).
// Writes x2 (fp32) and xn2 (fp32) to workspace.
// ---------------------------------------------------------------------------
__global__ __launch_bounds__(192) void k_proj_ln2(
    const float* __restrict__ x, const bf16* __restrict__ ctx,
    const float* __restrict__ wo, const float* __restrict__ bo,
    const float* __restrict__ g2, const float* __restrict__ lb2,
    float* __restrict__ x2, float* __restrict__ xn2)
{
    __shared__ float cl[8 * HK_];
    __shared__ float x2l[8 * D_];
    const int tid = threadIdx.x;
    const int rowbase = blockIdx.x * 8;
    cl[tid]       = b2f(ctx[(size_t)rowbase * HK_ + tid]);
    cl[tid + 192] = b2f(ctx[(size_t)rowbase * HK_ + tid + 192]);
    __syncthreads();

    const int d = tid;
    float acc[8];
    #pragma unroll
    for (int r = 0; r < 8; ++r) acc[r] = 0.f;
    for (int j = 0; j < HK_; j += 4) {
        const float w0 = wo[(j + 0) * D_ + d];
        const float w1 = wo[(j + 1) * D_ + d];
        const float w2 = wo[(j + 2) * D_ + d];
        const float w3 = wo[(j + 3) * D_ + d];
        #pragma unroll
        for (int r = 0; r < 8; ++r) {
            const float4 cv = *(const float4*)&cl[r * HK_ + j];
            acc[r] = fmaf(cv.x, w0, fmaf(cv.y, w1, fmaf(cv.z, w2, fmaf(cv.w, w3, acc[r]))));
        }
    }
    const float bod = bo[d];
    #pragma unroll
    for (int r = 0; r < 8; ++r) {
        const size_t idx = (size_t)(rowbase + r) * D_ + d;
        const float v = acc[r] + bod + x[idx];
        x2[idx] = v;
        x2l[r * D_ + d] = v;
    }
    __syncthreads();

    const int wave = tid >> 6, lane = tid & 63;
    for (int r = wave; r < 8; r += 3) {
        const float x0  = x2l[r * D_ + lane];
        const float x1  = x2l[r * D_ + lane + 64];
        const float xv2 = x2l[r * D_ + lane + 128];
        float s = x0 + x1 + xv2;
        float q = x0 * x0 + x1 * x1 + xv2 * xv2;
        #pragma unroll
        for (int m = 1; m < 64; m <<= 1) {
            s += __shfl_xor(s, m, 64);
            q += __shfl_xor(q, m, 64);
        }
        const float mean = s * (1.0f / 192.0f);
        const float var  = q * (1.0f / 192.0f) - mean * mean;
        const float rs   = rsqrtf(var + EPS_);
        const size_t ro = (size_t)(rowbase + r) * D_;
        xn2[ro + lane]       = (x0 - mean) * rs * g2[lane]       + lb2[lane];
        xn2[ro + lane + 64]  = (x1 - mean) * rs * g2[lane + 64]  + lb2[lane + 64];
        xn2[ro + lane + 128] = (xv2 - mean) * rs * g2[lane + 128] + lb2[lane + 128];
    }
}

// ---------------------------------------------------------------------------
// K4: conv1 (3-tap, D->D) + bias + relu -> hp (rows 0 and L-1 zeroed).
// 16 output rows/block, 192 threads (thread = out channel d). Activations via
// wave-uniform addresses (scalar path); weights coalesced per-lane. Edge tiles
// read one out-of-range row (guard gaps make it safe; result discarded).
// ---------------------------------------------------------------------------
__global__ __launch_bounds__(192) void k_conv1(
    const float* __restrict__ xn2, const float* __restrict__ w,
    const float* __restrict__ bias, float* __restrict__ hp)
{
    const int d  = threadIdx.x;
    const int bb = blockIdx.x >> 7;
    const int m0 = (blockIdx.x & 127) * 16;
    const int base = bb * L_ + m0 - 1;
    float acc[16];
    #pragma unroll
    for (int r = 0; r < 16; ++r) acc[r] = 0.f;
    for (int t = 0; t < 3; ++t) {
        const float* xp = xn2 + (long long)(base + t) * D_;
        for (int c = 0; c < D_; c += 4) {
            const float w0 = w[((t * D_ + c + 0) * D_) + d];
            const float w1 = w[((t * D_ + c + 1) * D_) + d];
            const float w2 = w[((t * D_ + c + 2) * D_) + d];
            const float w3 = w[((t * D_ + c + 3) * D_) + d];
            #pragma unroll
            for (int r = 0; r < 16; ++r) {
                const float* xr = xp + r * D_ + c;
                acc[r] = fmaf(xr[0], w0, fmaf(xr[1], w1, fmaf(xr[2], w2, fmaf(xr[3], w3, acc[r]))));
            }
        }
    }
    const float bd = bias[d];
    #pragma unroll
    for (int r = 0; r < 16; ++r) {
        const int m = m0 + r;
        float v = fmaxf(acc[r] + bd, 0.f);
        if (m == 0 || m == L_ - 1) v = 0.f;
        hp[(size_t)(bb * L_ + m) * D_ + d] = v;
    }
}

// ---------------------------------------------------------------------------
// K5: conv2 + bias + pad + final residual -> out (fp32, the reference dtype).
// ---------------------------------------------------------------------------
__global__ __launch_bounds__(192) void k_conv2(
    const float* __restrict__ hp, const float* __restrict__ x2,
    const float* __restrict__ w, const float* __restrict__ bias,
    float* __restrict__ out)
{
    const int d  = threadIdx.x;
    const int bb = blockIdx.x >> 7;
    const int m0 = (blockIdx.x & 127) * 16;
    const int base = bb * L_ + m0 - 1;
    float acc[16];
    #pragma unroll
    for (int r = 0; r < 16; ++r) acc[r] = 0.f;
    for (int t = 0; t < 3; ++t) {
        const float* xp = hp + (long long)(base + t) * D_;
        for (int c = 0; c < D_; c += 4) {
            const float w0 = w[((t * D_ + c + 0) * D_) + d];
            const float w1 = w[((t * D_ + c + 1) * D_) + d];
            const float w2 = w[((t * D_ + c + 2) * D_) + d];
            const float w3 = w[((t * D_ + c + 3) * D_) + d];
            #pragma unroll
            for (int r = 0; r < 16; ++r) {
                const float* xr = xp + r * D_ + c;
                acc[r] = fmaf(xr[0], w0, fmaf(xr[1], w1, fmaf(xr[2], w2, fmaf(xr[3], w3, acc[r]))));
            }
        }
    }
    const float bd = bias[d];
    #pragma unroll
    for (int r = 0; r < 16; ++r) {
        const int m = m0 + r;
        float v = x2[(size_t)(bb * L_ + m) * D_ + d];
        if (m != 0 && m != L_ - 1) v += acc[r] + bd;
        out[(size_t)(bb * L_ + m) * D_ + d] = v;
    }
}

// ---------------------------------------------------------------------------
extern "C" void kernel_launch(void* const* d_in, const int* in_sizes, int n_in,
                              void* d_out, int out_size, void* d_ws, size_t ws_size,
                              hipStream_t stream)
{
    const float* x    = (const float*)d_in[0];
    const float* ln1g = (const float*)d_in[1];
    const float* ln1b = (const float*)d_in[2];
    const float* wq   = (const float*)d_in[3];
    const float* bq   = (const float*)d_in[4];
    const float* wk   = (const float*)d_in[5];
    const float* bk   = (const float*)d_in[6];
    const float* wv   = (const float*)d_in[7];
    const float* bv   = (const float*)d_in[8];
    const float* wo   = (const float*)d_in[9];
    const float* bo   = (const float*)d_in[10];
    const float* ln2g = (const float*)d_in[11];
    const float* ln2b = (const float*)d_in[12];
    const float* c1w  = (const float*)d_in[13];
    const float* c1b  = (const float*)d_in[14];
    const float* c2w  = (const float*)d_in[15];
    const float* c2b  = (const float*)d_in[16];

    const size_t ROWS = (size_t)16 * L_;            // 32768
    char* ws = (char*)d_ws;
    size_t off = 4096;                               // guard (conv row -1)
    float* xn2 = (float*)(ws + off); off += ROWS * D_ * 4;   // 25.2 MB
    off += 4096;                                     // guard
    float* hp  = (float*)(ws + off); off += ROWS * D_ * 4;   // 25.2 MB
    off += 4096;                                     // guard
    float* x2  = (float*)(ws + off); off += ROWS * D_ * 4;   // 25.2 MB
    bf16* qb   = (bf16*)(ws + off);  off += ROWS * HK_ * 2;  // 3.15 MB
    bf16* kb   = (bf16*)(ws + off);  off += ROWS * HK_ * 2;
    bf16* vb2  = (bf16*)(ws + off);  off += ROWS * HK_ * 2;
    bf16* ctx  = (bf16*)(ws + off);  off += ROWS * HK_ * 2;  // total ~89 MB

    k_ln_qkv  <<<2048, 256, 0, stream>>>(x, ln1g, ln1b, wq, bq, wk, bk, wv, bv, qb, kb, vb2);
    k_attn    <<< 512, 128, 0, stream>>>(qb, kb, vb2, ctx);
    k_proj_ln2<<<4096, 192, 0, stream>>>(x, ctx, wo, bo, ln2g, ln2b, x2, xn2);
    k_conv1   <<<2048, 192, 0, stream>>>(xn2, c1w, c1b, hp);
    k_conv2   <<<2048, 192, 0, stream>>>(hp, x2, c2w, c2b, (float*)d_out);
}

// Round 4
// 703.844 us; speedup vs baseline: 1.4097x; 1.4097x over previous
//
#include <hip/hip_runtime.h>
#include <hip/hip_bf16.h>

#define L_ 2048
#define D_ 192
#define HK_ 48
#define EPS_ 1e-3f
#define SCALE_ 0.28867513459481287f  // 1/sqrt(12)

typedef __hip_bfloat16 bf16;

__device__ __forceinline__ float b2f(bf16 x) { return __bfloat162float(x); }
__device__ __forceinline__ bf16 f2b(float x) { return __float2bfloat16(x); }
__device__ __forceinline__ float us2f(unsigned short u) {
    union { unsigned u; float f; } c; c.u = ((unsigned)u) << 16; return c.f;
}

// ---------------------------------------------------------------------------
// K1: LN1 + QKV projection. 16 rows/block, 256 threads.
// ---------------------------------------------------------------------------
__global__ __launch_bounds__(256) void k_ln_qkv(
    const float* __restrict__ x, const float* __restrict__ g1, const float* __restrict__ b1,
    const float* __restrict__ wq, const float* __restrict__ bq,
    const float* __restrict__ wk, const float* __restrict__ bk,
    const float* __restrict__ wv, const float* __restrict__ bv,
    bf16* __restrict__ qo, bf16* __restrict__ ko, bf16* __restrict__ vo)
{
    __shared__ float xn[16 * D_];
    const int tid = threadIdx.x;
    const int wave = tid >> 6, lane = tid & 63;
    const int rowbase = blockIdx.x * 16;

    #pragma unroll
    for (int i = 0; i < 4; ++i) {
        const int r = wave * 4 + i;
        const float* xp = x + (size_t)(rowbase + r) * D_;
        const float x0 = xp[lane];
        const float x1 = xp[lane + 64];
        const float x2 = xp[lane + 128];
        float s = x0 + x1 + x2;
        float q = x0 * x0 + x1 * x1 + x2 * x2;
        #pragma unroll
        for (int m = 1; m < 64; m <<= 1) {
            s += __shfl_xor(s, m, 64);
            q += __shfl_xor(q, m, 64);
        }
        const float mean = s * (1.0f / 192.0f);
        const float var  = q * (1.0f / 192.0f) - mean * mean;
        const float rs   = rsqrtf(var + EPS_);
        xn[r * D_ + lane]       = (x0 - mean) * rs * g1[lane]       + b1[lane];
        xn[r * D_ + lane + 64]  = (x1 - mean) * rs * g1[lane + 64]  + b1[lane + 64];
        xn[r * D_ + lane + 128] = (x2 - mean) * rs * g1[lane + 128] + b1[lane + 128];
    }
    __syncthreads();

    if (tid < 144) {
        const int sel = tid / 48, col = tid % 48;
        const float* W  = sel == 0 ? wq : (sel == 1 ? wk : wv);
        const float* Bp = sel == 0 ? bq : (sel == 1 ? bk : bv);
        bf16* O         = sel == 0 ? qo : (sel == 1 ? ko : vo);
        float acc[16];
        #pragma unroll
        for (int r = 0; r < 16; ++r) acc[r] = 0.f;
        for (int c = 0; c < D_; c += 4) {
            const float w0 = W[(c + 0) * HK_ + col];
            const float w1 = W[(c + 1) * HK_ + col];
            const float w2 = W[(c + 2) * HK_ + col];
            const float w3 = W[(c + 3) * HK_ + col];
            #pragma unroll
            for (int r = 0; r < 16; ++r) {
                const float4 xv = *(const float4*)&xn[r * D_ + c];
                acc[r] = fmaf(xv.x, w0, fmaf(xv.y, w1, fmaf(xv.z, w2, fmaf(xv.w, w3, acc[r]))));
            }
        }
        const float bb = Bp[col];
        #pragma unroll
        for (int r = 0; r < 16; ++r)
            O[(size_t)(rowbase + r) * HK_ + col] = f2b(acc[r] + bb);
    }
}

// ---------------------------------------------------------------------------
// K2a: attention partials. Block = (bh, qtile, ktile) causal tile pair,
// qtile/ktile = 256 queries/keys. 2304 uniform blocks, 128 threads,
// 2 adjacent queries/thread. K/V tile staged once in 24 KB LDS.
// Fixed-max softmax p=exp(s-8): partial (l, o) combine by plain addition.
// Causality via loop bounds: off-diag tiles run all 256 keys unmasked;
// diagonal tiles run klim = 2t+1 keys + one q1-only tail key.
// ---------------------------------------------------------------------------
__global__ __launch_bounds__(128) void k_attn_part(
    const bf16* __restrict__ qb, const bf16* __restrict__ kb, const bf16* __restrict__ vb,
    bf16* __restrict__ part_o, float* __restrict__ part_l)
{
    __shared__ float Kl[256 * 12];
    __shared__ float Vl[256 * 12];
    const int tid = threadIdx.x;
    const int bh  = blockIdx.x / 36;
    int r = blockIdx.x % 36;
    int qt = 0;
    while (r >= qt + 1) { r -= qt + 1; ++qt; }
    const int ks = r;
    const int b = bh >> 2, h = bh & 3;
    const size_t base = (size_t)b * L_ * HK_ + h * 12;

    // stage 256-key K/V slice (bf16 -> fp32 LDS)
    for (int rr = tid; rr < 256; rr += 128) {
        const size_t off = base + (size_t)(ks * 256 + rr) * HK_;
        const ushort4* kp = (const ushort4*)(kb + off);
        const ushort4* vp = (const ushort4*)(vb + off);
        #pragma unroll
        for (int j = 0; j < 3; ++j) {
            const ushort4 kv = kp[j];
            const ushort4 vv = vp[j];
            Kl[rr * 12 + 4 * j + 0] = us2f(kv.x);
            Kl[rr * 12 + 4 * j + 1] = us2f(kv.y);
            Kl[rr * 12 + 4 * j + 2] = us2f(kv.z);
            Kl[rr * 12 + 4 * j + 3] = us2f(kv.w);
            Vl[rr * 12 + 4 * j + 0] = us2f(vv.x);
            Vl[rr * 12 + 4 * j + 1] = us2f(vv.y);
            Vl[rr * 12 + 4 * j + 2] = us2f(vv.z);
            Vl[rr * 12 + 4 * j + 3] = us2f(vv.w);
        }
    }

    const int q0 = qt * 256 + 2 * tid, q1 = q0 + 1;
    float qr0[12], qr1[12], o0[12], o1[12];
    {
        const bf16* qp = qb + base + (size_t)q0 * HK_;
        #pragma unroll
        for (int i = 0; i < 12; ++i) {
            qr0[i] = b2f(qp[i]);
            qr1[i] = b2f(qp[HK_ + i]);
            o0[i] = 0.f; o1[i] = 0.f;
        }
    }
    __syncthreads();

    const bool diag = (ks == qt);
    const int n_both = diag ? (2 * tid + 1) : 256;
    float l0 = 0.f, l1 = 0.f;
    for (int kk = 0; kk < n_both; ++kk) {
        float kr[12], vr[12];
        *(float4*)&kr[0] = *(const float4*)&Kl[kk * 12 + 0];
        *(float4*)&kr[4] = *(const float4*)&Kl[kk * 12 + 4];
        *(float4*)&kr[8] = *(const float4*)&Kl[kk * 12 + 8];
        // 2-way split score chains for ILP
        float a0 = 0.f, a1 = 0.f, c0 = 0.f, c1 = 0.f;
        #pragma unroll
        for (int i = 0; i < 6; ++i) {
            a0 = fmaf(qr0[i], kr[i], a0);
            c0 = fmaf(qr0[i + 6], kr[i + 6], c0);
            a1 = fmaf(qr1[i], kr[i], a1);
            c1 = fmaf(qr1[i + 6], kr[i + 6], c1);
        }
        const float p0 = __expf((a0 + c0) * SCALE_ - 8.0f);
        const float p1 = __expf((a1 + c1) * SCALE_ - 8.0f);
        l0 += p0; l1 += p1;
        *(float4*)&vr[0] = *(const float4*)&Vl[kk * 12 + 0];
        *(float4*)&vr[4] = *(const float4*)&Vl[kk * 12 + 4];
        *(float4*)&vr[8] = *(const float4*)&Vl[kk * 12 + 8];
        #pragma unroll
        for (int i = 0; i < 12; ++i) {
            o0[i] = fmaf(p0, vr[i], o0[i]);
            o1[i] = fmaf(p1, vr[i], o1[i]);
        }
    }
    if (diag) {                      // tail key (= q1's own position), q1 only
        const int kk = n_both;
        float a1 = 0.f, c1 = 0.f;
        #pragma unroll
        for (int i = 0; i < 6; ++i) {
            a1 = fmaf(qr1[i], Kl[kk * 12 + i], a1);
            c1 = fmaf(qr1[i + 6], Kl[kk * 12 + i + 6], c1);
        }
        const float p1 = __expf((a1 + c1) * SCALE_ - 8.0f);
        l1 += p1;
        #pragma unroll
        for (int i = 0; i < 12; ++i)
            o1[i] = fmaf(p1, Vl[kk * 12 + i], o1[i]);
    }

    // write partials: part_o[bh][q][slice][12] bf16, part_l[bh][q][8] f32
    const size_t slot = ((size_t)bh * L_ + q0) * 8 + ks;
    part_l[slot]     = l0;
    part_l[slot + 8] = l1;
    bf16* op = part_o + slot * 12;
    #pragma unroll
    for (int i = 0; i < 12; ++i) {
        op[i]      = f2b(o0[i]);
        op[96 + i] = f2b(o1[i]);
    }
}

// ---------------------------------------------------------------------------
// K2b: combine partials -> ctx (bf16). Thread = (bh, q). ns = q/256 + 1.
// ---------------------------------------------------------------------------
__global__ __launch_bounds__(256) void k_attn_comb(
    const bf16* __restrict__ part_o, const float* __restrict__ part_l,
    bf16* __restrict__ ctx)
{
    const int idx = blockIdx.x * 256 + threadIdx.x;   // bh*L + q
    const int bh = idx >> 11, q = idx & 2047;
    const int b = bh >> 2, h = bh & 3;
    const int ns = (q >> 8) + 1;
    const bf16* op = part_o + (size_t)idx * 96;
    const float* lp = part_l + (size_t)idx * 8;
    float l = 0.f, o[12];
    #pragma unroll
    for (int i = 0; i < 12; ++i) o[i] = 0.f;
    for (int s = 0; s < ns; ++s) {
        l += lp[s];
        #pragma unroll
        for (int i = 0; i < 12; ++i) o[i] += b2f(op[s * 12 + i]);
    }
    const float inv = 1.0f / l;
    bf16* cp = ctx + ((size_t)b * L_ + q) * HK_ + h * 12;
    #pragma unroll
    for (int i = 0; i < 12; ++i) cp[i] = f2b(o[i] * inv);
}

// ---------------------------------------------------------------------------
// K3: out-proj + residual + LN2. 8 rows/block, 192 threads (thread = channel).
// ---------------------------------------------------------------------------
__global__ __launch_bounds__(192) void k_proj_ln2(
    const float* __restrict__ x, const bf16* __restrict__ ctx,
    const float* __restrict__ wo, const float* __restrict__ bo,
    const float* __restrict__ g2, const float* __restrict__ lb2,
    float* __restrict__ x2, float* __restrict__ xn2)
{
    __shared__ float cl[8 * HK_];
    __shared__ float x2l[8 * D_];
    const int tid = threadIdx.x;
    const int rowbase = blockIdx.x * 8;
    cl[tid]       = b2f(ctx[(size_t)rowbase * HK_ + tid]);
    cl[tid + 192] = b2f(ctx[(size_t)rowbase * HK_ + tid + 192]);
    __syncthreads();

    const int d = tid;
    float acc[8];
    #pragma unroll
    for (int r = 0; r < 8; ++r) acc[r] = 0.f;
    for (int j = 0; j < HK_; j += 4) {
        const float w0 = wo[(j + 0) * D_ + d];
        const float w1 = wo[(j + 1) * D_ + d];
        const float w2 = wo[(j + 2) * D_ + d];
        const float w3 = wo[(j + 3) * D_ + d];
        #pragma unroll
        for (int r = 0; r < 8; ++r) {
            const float4 cv = *(const float4*)&cl[r * HK_ + j];
            acc[r] = fmaf(cv.x, w0, fmaf(cv.y, w1, fmaf(cv.z, w2, fmaf(cv.w, w3, acc[r]))));
        }
    }
    const float bod = bo[d];
    #pragma unroll
    for (int r = 0; r < 8; ++r) {
        const size_t idx = (size_t)(rowbase + r) * D_ + d;
        const float v = acc[r] + bod + x[idx];
        x2[idx] = v;
        x2l[r * D_ + d] = v;
    }
    __syncthreads();

    const int wave = tid >> 6, lane = tid & 63;
    for (int r = wave; r < 8; r += 3) {
        const float x0  = x2l[r * D_ + lane];
        const float x1  = x2l[r * D_ + lane + 64];
        const float xv2 = x2l[r * D_ + lane + 128];
        float s = x0 + x1 + xv2;
        float q = x0 * x0 + x1 * x1 + xv2 * xv2;
        #pragma unroll
        for (int m = 1; m < 64; m <<= 1) {
            s += __shfl_xor(s, m, 64);
            q += __shfl_xor(q, m, 64);
        }
        const float mean = s * (1.0f / 192.0f);
        const float var  = q * (1.0f / 192.0f) - mean * mean;
        const float rs   = rsqrtf(var + EPS_);
        const size_t ro = (size_t)(rowbase + r) * D_;
        xn2[ro + lane]       = (x0 - mean) * rs * g2[lane]       + lb2[lane];
        xn2[ro + lane + 64]  = (x1 - mean) * rs * g2[lane + 64]  + lb2[lane + 64];
        xn2[ro + lane + 128] = (xv2 - mean) * rs * g2[lane + 128] + lb2[lane + 128];
    }
}

// ---------------------------------------------------------------------------
// K4: conv1 (3-tap, D->D) + bias + relu -> hp (rows 0 and L-1 zeroed).
// ---------------------------------------------------------------------------
__global__ __launch_bounds__(192) void k_conv1(
    const float* __restrict__ xn2, const float* __restrict__ w,
    const float* __restrict__ bias, float* __restrict__ hp)
{
    const int d  = threadIdx.x;
    const int bb = blockIdx.x >> 7;
    const int m0 = (blockIdx.x & 127) * 16;
    const int base = bb * L_ + m0 - 1;
    float acc[16];
    #pragma unroll
    for (int r = 0; r < 16; ++r) acc[r] = 0.f;
    for (int t = 0; t < 3; ++t) {
        const float* xp = xn2 + (long long)(base + t) * D_;
        for (int c = 0; c < D_; c += 4) {
            const float w0 = w[((t * D_ + c + 0) * D_) + d];
            const float w1 = w[((t * D_ + c + 1) * D_) + d];
            const float w2 = w[((t * D_ + c + 2) * D_) + d];
            const float w3 = w[((t * D_ + c + 3) * D_) + d];
            #pragma unroll
            for (int r = 0; r < 16; ++r) {
                const float* xr = xp + r * D_ + c;
                acc[r] = fmaf(xr[0], w0, fmaf(xr[1], w1, fmaf(xr[2], w2, fmaf(xr[3], w3, acc[r]))));
            }
        }
    }
    const float bd = bias[d];
    #pragma unroll
    for (int r = 0; r < 16; ++r) {
        const int m = m0 + r;
        float v = fmaxf(acc[r] + bd, 0.f);
        if (m == 0 || m == L_ - 1) v = 0.f;
        hp[(size_t)(bb * L_ + m) * D_ + d] = v;
    }
}

// ---------------------------------------------------------------------------
// K5: conv2 + bias + pad + final residual -> out (fp32).
// ---------------------------------------------------------------------------
__global__ __launch_bounds__(192) void k_conv2(
    const float* __restrict__ hp, const float* __restrict__ x2,
    const float* __restrict__ w, const float* __restrict__ bias,
    float* __restrict__ out)
{
    const int d  = threadIdx.x;
    const int bb = blockIdx.x >> 7;
    const int m0 = (blockIdx.x & 127) * 16;
    const int base = bb * L_ + m0 - 1;
    float acc[16];
    #pragma unroll
    for (int r = 0; r < 16; ++r) acc[r] = 0.f;
    for (int t = 0; t < 3; ++t) {
        const float* xp = hp + (long long)(base + t) * D_;
        for (int c = 0; c < D_; c += 4) {
            const float w0 = w[((t * D_ + c + 0) * D_) + d];
            const float w1 = w[((t * D_ + c + 1) * D_) + d];
            const float w2 = w[((t * D_ + c + 2) * D_) + d];
            const float w3 = w[((t * D_ + c + 3) * D_) + d];
            #pragma unroll
            for (int r = 0; r < 16; ++r) {
                const float* xr = xp + r * D_ + c;
                acc[r] = fmaf(xr[0], w0, fmaf(xr[1], w1, fmaf(xr[2], w2, fmaf(xr[3], w3, acc[r]))));
            }
        }
    }
    const float bd = bias[d];
    #pragma unroll
    for (int r = 0; r < 16; ++r) {
        const int m = m0 + r;
        float v = x2[(size_t)(bb * L_ + m) * D_ + d];
        if (m != 0 && m != L_ - 1) v += acc[r] + bd;
        out[(size_t)(bb * L_ + m) * D_ + d] = v;
    }
}

// ---------------------------------------------------------------------------
extern "C" void kernel_launch(void* const* d_in, const int* in_sizes, int n_in,
                              void* d_out, int out_size, void* d_ws, size_t ws_size,
                              hipStream_t stream)
{
    const float* x    = (const float*)d_in[0];
    const float* ln1g = (const float*)d_in[1];
    const float* ln1b = (const float*)d_in[2];
    const float* wq   = (const float*)d_in[3];
    const float* bq   = (const float*)d_in[4];
    const float* wk   = (const float*)d_in[5];
    const float* bk   = (const float*)d_in[6];
    const float* wv   = (const float*)d_in[7];
    const float* bv   = (const float*)d_in[8];
    const float* wo   = (const float*)d_in[9];
    const float* bo   = (const float*)d_in[10];
    const float* ln2g = (const float*)d_in[11];
    const float* ln2b = (const float*)d_in[12];
    const float* c1w  = (const float*)d_in[13];
    const float* c1b  = (const float*)d_in[14];
    const float* c2w  = (const float*)d_in[15];
    const float* c2b  = (const float*)d_in[16];

    const size_t ROWS = (size_t)16 * L_;            // 32768
    char* ws = (char*)d_ws;
    size_t off = 4096;                               // guard (conv row -1)
    float* xn2 = (float*)(ws + off); off += ROWS * D_ * 4;   // 25.2 MB
    off += 4096;                                     // guard
    float* hp  = (float*)(ws + off); off += ROWS * D_ * 4;   // 25.2 MB
    off += 4096;                                     // guard
    float* x2  = (float*)(ws + off); off += ROWS * D_ * 4;   // 25.2 MB
    bf16* qb   = (bf16*)(ws + off);  off += ROWS * HK_ * 2;  // 3.15 MB
    bf16* kb   = (bf16*)(ws + off);  off += ROWS * HK_ * 2;
    bf16* vb2  = (bf16*)(ws + off);  off += ROWS * HK_ * 2;
    bf16* ctx  = (bf16*)(ws + off);  off += ROWS * HK_ * 2;  // total ~89 MB

    // attention partials ALIAS conv scratch (consumed before xn2/hp written):
    // part_o: 64*2048*8 slices * 12 bf16 = 25,165,824 B  (== xn2 region)
    // part_l: 64*2048*8 f32              =  4,194,304 B  (start of hp region)
    bf16*  part_o = (bf16*)xn2;
    float* part_l = (float*)hp;

    k_ln_qkv   <<<2048, 256, 0, stream>>>(x, ln1g, ln1b, wq, bq, wk, bk, wv, bv, qb, kb, vb2);
    k_attn_part<<<64 * 36, 128, 0, stream>>>(qb, kb, vb2, part_o, part_l);
    k_attn_comb<<< 512, 256, 0, stream>>>(part_o, part_l, ctx);
    k_proj_ln2 <<<4096, 192, 0, stream>>>(x, ctx, wo, bo, ln2g, ln2b, x2, xn2);
    k_conv1    <<<2048, 192, 0, stream>>>(xn2, c1w, c1b, hp);
    k_conv2    <<<2048, 192, 0, stream>>>(hp, x2, c2w, c2b, (float*)d_out);
}

// Round 5
// 367.161 us; speedup vs baseline: 2.7023x; 1.9170x over previous
//
#include <hip/hip_runtime.h>
#include <hip/hip_bf16.h>

#define L_ 2048
#define D_ 192
#define HK_ 48
#define EPS_ 1e-3f
#define SCALE_ 0.28867513459481287f  // 1/sqrt(12)

typedef __hip_bfloat16 bf16;
typedef __bf16 bf16x8 __attribute__((ext_vector_type(8)));
typedef float  f32x4  __attribute__((ext_vector_type(4)));

__device__ __forceinline__ float b2f(bf16 x) { return __bfloat162float(x); }
__device__ __forceinline__ bf16 f2b(float x) { return __float2bfloat16(x); }
__device__ __forceinline__ float us2f(unsigned short u) {
    union { unsigned u; float f; } c; c.u = ((unsigned)u) << 16; return c.f;
}

// ---------------------------------------------------------------------------
// K1: LN1 + QKV projection. 16 rows/block, 256 threads.
// ---------------------------------------------------------------------------
__global__ __launch_bounds__(256) void k_ln_qkv(
    const float* __restrict__ x, const float* __restrict__ g1, const float* __restrict__ b1,
    const float* __restrict__ wq, const float* __restrict__ bq,
    const float* __restrict__ wk, const float* __restrict__ bk,
    const float* __restrict__ wv, const float* __restrict__ bv,
    bf16* __restrict__ qo, bf16* __restrict__ ko, bf16* __restrict__ vo)
{
    __shared__ float xn[16 * D_];
    const int tid = threadIdx.x;
    const int wave = tid >> 6, lane = tid & 63;
    const int rowbase = blockIdx.x * 16;

    #pragma unroll
    for (int i = 0; i < 4; ++i) {
        const int r = wave * 4 + i;
        const float* xp = x + (size_t)(rowbase + r) * D_;
        const float x0 = xp[lane];
        const float x1 = xp[lane + 64];
        const float x2 = xp[lane + 128];
        float s = x0 + x1 + x2;
        float q = x0 * x0 + x1 * x1 + x2 * x2;
        #pragma unroll
        for (int m = 1; m < 64; m <<= 1) {
            s += __shfl_xor(s, m, 64);
            q += __shfl_xor(q, m, 64);
        }
        const float mean = s * (1.0f / 192.0f);
        const float var  = q * (1.0f / 192.0f) - mean * mean;
        const float rs   = rsqrtf(var + EPS_);
        xn[r * D_ + lane]       = (x0 - mean) * rs * g1[lane]       + b1[lane];
        xn[r * D_ + lane + 64]  = (x1 - mean) * rs * g1[lane + 64]  + b1[lane + 64];
        xn[r * D_ + lane + 128] = (x2 - mean) * rs * g1[lane + 128] + b1[lane + 128];
    }
    __syncthreads();

    if (tid < 144) {
        const int sel = tid / 48, col = tid % 48;
        const float* W  = sel == 0 ? wq : (sel == 1 ? wk : wv);
        const float* Bp = sel == 0 ? bq : (sel == 1 ? bk : bv);
        bf16* O         = sel == 0 ? qo : (sel == 1 ? ko : vo);
        float acc[16];
        #pragma unroll
        for (int r = 0; r < 16; ++r) acc[r] = 0.f;
        for (int c = 0; c < D_; c += 4) {
            const float w0 = W[(c + 0) * HK_ + col];
            const float w1 = W[(c + 1) * HK_ + col];
            const float w2 = W[(c + 2) * HK_ + col];
            const float w3 = W[(c + 3) * HK_ + col];
            #pragma unroll
            for (int r = 0; r < 16; ++r) {
                const float4 xv = *(const float4*)&xn[r * D_ + c];
                acc[r] = fmaf(xv.x, w0, fmaf(xv.y, w1, fmaf(xv.z, w2, fmaf(xv.w, w3, acc[r]))));
            }
        }
        const float bb = Bp[col];
        #pragma unroll
        for (int r = 0; r < 16; ++r)
            O[(size_t)(rowbase + r) * HK_ + col] = f2b(acc[r] + bb);
    }
}

// ---------------------------------------------------------------------------
// K2a: attention partials (unchanged from round 4).
// ---------------------------------------------------------------------------
__global__ __launch_bounds__(128) void k_attn_part(
    const bf16* __restrict__ qb, const bf16* __restrict__ kb, const bf16* __restrict__ vb,
    bf16* __restrict__ part_o, float* __restrict__ part_l)
{
    __shared__ float Kl[256 * 12];
    __shared__ float Vl[256 * 12];
    const int tid = threadIdx.x;
    const int bh  = blockIdx.x / 36;
    int r = blockIdx.x % 36;
    int qt = 0;
    while (r >= qt + 1) { r -= qt + 1; ++qt; }
    const int ks = r;
    const int b = bh >> 2, h = bh & 3;
    const size_t base = (size_t)b * L_ * HK_ + h * 12;

    for (int rr = tid; rr < 256; rr += 128) {
        const size_t off = base + (size_t)(ks * 256 + rr) * HK_;
        const ushort4* kp = (const ushort4*)(kb + off);
        const ushort4* vp = (const ushort4*)(vb + off);
        #pragma unroll
        for (int j = 0; j < 3; ++j) {
            const ushort4 kv = kp[j];
            const ushort4 vv = vp[j];
            Kl[rr * 12 + 4 * j + 0] = us2f(kv.x);
            Kl[rr * 12 + 4 * j + 1] = us2f(kv.y);
            Kl[rr * 12 + 4 * j + 2] = us2f(kv.z);
            Kl[rr * 12 + 4 * j + 3] = us2f(kv.w);
            Vl[rr * 12 + 4 * j + 0] = us2f(vv.x);
            Vl[rr * 12 + 4 * j + 1] = us2f(vv.y);
            Vl[rr * 12 + 4 * j + 2] = us2f(vv.z);
            Vl[rr * 12 + 4 * j + 3] = us2f(vv.w);
        }
    }

    const int q0 = qt * 256 + 2 * tid;
    float qr0[12], qr1[12], o0[12], o1[12];
    {
        const bf16* qp = qb + base + (size_t)q0 * HK_;
        #pragma unroll
        for (int i = 0; i < 12; ++i) {
            qr0[i] = b2f(qp[i]);
            qr1[i] = b2f(qp[HK_ + i]);
            o0[i] = 0.f; o1[i] = 0.f;
        }
    }
    __syncthreads();

    const bool diag = (ks == qt);
    const int n_both = diag ? (2 * tid + 1) : 256;
    float l0 = 0.f, l1 = 0.f;
    for (int kk = 0; kk < n_both; ++kk) {
        float kr[12], vr[12];
        *(float4*)&kr[0] = *(const float4*)&Kl[kk * 12 + 0];
        *(float4*)&kr[4] = *(const float4*)&Kl[kk * 12 + 4];
        *(float4*)&kr[8] = *(const float4*)&Kl[kk * 12 + 8];
        float a0 = 0.f, a1 = 0.f, c0 = 0.f, c1 = 0.f;
        #pragma unroll
        for (int i = 0; i < 6; ++i) {
            a0 = fmaf(qr0[i], kr[i], a0);
            c0 = fmaf(qr0[i + 6], kr[i + 6], c0);
            a1 = fmaf(qr1[i], kr[i], a1);
            c1 = fmaf(qr1[i + 6], kr[i + 6], c1);
        }
        const float p0 = __expf((a0 + c0) * SCALE_ - 8.0f);
        const float p1 = __expf((a1 + c1) * SCALE_ - 8.0f);
        l0 += p0; l1 += p1;
        *(float4*)&vr[0] = *(const float4*)&Vl[kk * 12 + 0];
        *(float4*)&vr[4] = *(const float4*)&Vl[kk * 12 + 4];
        *(float4*)&vr[8] = *(const float4*)&Vl[kk * 12 + 8];
        #pragma unroll
        for (int i = 0; i < 12; ++i) {
            o0[i] = fmaf(p0, vr[i], o0[i]);
            o1[i] = fmaf(p1, vr[i], o1[i]);
        }
    }
    if (diag) {
        const int kk = n_both;
        float a1 = 0.f, c1 = 0.f;
        #pragma unroll
        for (int i = 0; i < 6; ++i) {
            a1 = fmaf(qr1[i], Kl[kk * 12 + i], a1);
            c1 = fmaf(qr1[i + 6], Kl[kk * 12 + i + 6], c1);
        }
        const float p1 = __expf((a1 + c1) * SCALE_ - 8.0f);
        l1 += p1;
        #pragma unroll
        for (int i = 0; i < 12; ++i)
            o1[i] = fmaf(p1, Vl[kk * 12 + i], o1[i]);
    }

    const size_t slot = ((size_t)bh * L_ + q0) * 8 + ks;
    part_l[slot]     = l0;
    part_l[slot + 8] = l1;
    bf16* op = part_o + slot * 12;
    #pragma unroll
    for (int i = 0; i < 12; ++i) {
        op[i]      = f2b(o0[i]);
        op[96 + i] = f2b(o1[i]);
    }
}

// ---------------------------------------------------------------------------
// K2b: combine partials -> ctx (bf16).
// ---------------------------------------------------------------------------
__global__ __launch_bounds__(256) void k_attn_comb(
    const bf16* __restrict__ part_o, const float* __restrict__ part_l,
    bf16* __restrict__ ctx)
{
    const int idx = blockIdx.x * 256 + threadIdx.x;   // bh*L + q
    const int bh = idx >> 11, q = idx & 2047;
    const int b = bh >> 2, h = bh & 3;
    const int ns = (q >> 8) + 1;
    const bf16* op = part_o + (size_t)idx * 96;
    const float* lp = part_l + (size_t)idx * 8;
    float l = 0.f, o[12];
    #pragma unroll
    for (int i = 0; i < 12; ++i) o[i] = 0.f;
    for (int s = 0; s < ns; ++s) {
        l += lp[s];
        #pragma unroll
        for (int i = 0; i < 12; ++i) o[i] += b2f(op[s * 12 + i]);
    }
    const float inv = 1.0f / l;
    bf16* cp = ctx + ((size_t)b * L_ + q) * HK_ + h * 12;
    #pragma unroll
    for (int i = 0; i < 12; ++i) cp[i] = f2b(o[i] * inv);
}

// ---------------------------------------------------------------------------
// K3: out-proj + residual + LN2 -> x2 (fp32) + xn2b (bf16).
// ---------------------------------------------------------------------------
__global__ __launch_bounds__(192) void k_proj_ln2(
    const float* __restrict__ x, const bf16* __restrict__ ctx,
    const float* __restrict__ wo, const float* __restrict__ bo,
    const float* __restrict__ g2, const float* __restrict__ lb2,
    float* __restrict__ x2, bf16* __restrict__ xn2b)
{
    __shared__ float cl[8 * HK_];
    __shared__ float x2l[8 * D_];
    const int tid = threadIdx.x;
    const int rowbase = blockIdx.x * 8;
    cl[tid]       = b2f(ctx[(size_t)rowbase * HK_ + tid]);
    cl[tid + 192] = b2f(ctx[(size_t)rowbase * HK_ + tid + 192]);
    __syncthreads();

    const int d = tid;
    float acc[8];
    #pragma unroll
    for (int r = 0; r < 8; ++r) acc[r] = 0.f;
    for (int j = 0; j < HK_; j += 4) {
        const float w0 = wo[(j + 0) * D_ + d];
        const float w1 = wo[(j + 1) * D_ + d];
        const float w2 = wo[(j + 2) * D_ + d];
        const float w3 = wo[(j + 3) * D_ + d];
        #pragma unroll
        for (int r = 0; r < 8; ++r) {
            const float4 cv = *(const float4*)&cl[r * HK_ + j];
            acc[r] = fmaf(cv.x, w0, fmaf(cv.y, w1, fmaf(cv.z, w2, fmaf(cv.w, w3, acc[r]))));
        }
    }
    const float bod = bo[d];
    #pragma unroll
    for (int r = 0; r < 8; ++r) {
        const size_t idx = (size_t)(rowbase + r) * D_ + d;
        const float v = acc[r] + bod + x[idx];
        x2[idx] = v;
        x2l[r * D_ + d] = v;
    }
    __syncthreads();

    const int wave = tid >> 6, lane = tid & 63;
    for (int r = wave; r < 8; r += 3) {
        const float x0  = x2l[r * D_ + lane];
        const float x1  = x2l[r * D_ + lane + 64];
        const float xv2 = x2l[r * D_ + lane + 128];
        float s = x0 + x1 + xv2;
        float q = x0 * x0 + x1 * x1 + xv2 * xv2;
        #pragma unroll
        for (int m = 1; m < 64; m <<= 1) {
            s += __shfl_xor(s, m, 64);
            q += __shfl_xor(q, m, 64);
        }
        const float mean = s * (1.0f / 192.0f);
        const float var  = q * (1.0f / 192.0f) - mean * mean;
        const float rs   = rsqrtf(var + EPS_);
        const size_t ro = (size_t)(rowbase + r) * D_;
        xn2b[ro + lane]       = f2b((x0 - mean) * rs * g2[lane]       + lb2[lane]);
        xn2b[ro + lane + 64]  = f2b((x1 - mean) * rs * g2[lane + 64]  + lb2[lane + 64]);
        xn2b[ro + lane + 128] = f2b((xv2 - mean) * rs * g2[lane + 128] + lb2[lane + 128]);
    }
}

// ---------------------------------------------------------------------------
// K-prep: repack conv weight [576][192] fp32 -> bf16 W'[kb][n][kk], kk=k%32.
// Makes the MFMA B-fragment a single contiguous 16-B load per lane.
// ---------------------------------------------------------------------------
__global__ __launch_bounds__(256) void k_wprep(
    const float* __restrict__ w, bf16* __restrict__ wr)
{
    const int i = blockIdx.x * 256 + threadIdx.x;   // i = k*192 + n
    if (i < 576 * 192) {
        const int k = i / 192, n = i - k * 192;
        wr[((size_t)(k >> 5) * 192 + n) * 32 + (k & 31)] = f2b(w[i]);
    }
}

// ---------------------------------------------------------------------------
// K4/K5: conv as MFMA GEMM. Block = 64 rows x 192 cols, 256 threads (4 waves).
// Wave w: rows rowbase+w*16..+15, all 12 n-tiles, acc[12] f32x4.
// K = 576 = 3 taps x 6 chunks of 32. A-frag: act[row + t-1][cb + q*8..],
// B-frag: W'[kb][n][kk] (both single 16-B loads per lane).
// MFMA layouts: A[m=lane&15][k=q*8+j], B[k=q*8+j][n=lane&15],
//               D[row=q*4+reg][col=lane&15].
// Edge rows (m==0, m==L-1) computed on guard garbage, overwritten per padding.
// ---------------------------------------------------------------------------
template <int IS_CONV1>
__global__ __launch_bounds__(256) void k_conv_mfma(
    const bf16* __restrict__ act, const bf16* __restrict__ wrep,
    const float* __restrict__ bias, const float* __restrict__ x2,
    bf16* __restrict__ outb, float* __restrict__ outf)
{
    const int wave = threadIdx.x >> 6, lane = threadIdx.x & 63;
    const int m16 = lane & 15, q = lane >> 4;
    const int rowbase = blockIdx.x * 64 + wave * 16;

    f32x4 acc[12];
    #pragma unroll
    for (int nt = 0; nt < 12; ++nt) acc[nt] = (f32x4){0.f, 0.f, 0.f, 0.f};

    #pragma unroll
    for (int t = 0; t < 3; ++t) {
        const long long arow = (long long)rowbase + m16 + t - 1;
        const bf16* ap = act + arow * D_ + q * 8;
        #pragma unroll
        for (int c6 = 0; c6 < 6; ++c6) {
            const int kb = t * 6 + c6;
            const bf16x8 a = *(const bf16x8*)(ap + c6 * 32);
            const bf16* wp = wrep + ((size_t)kb * 192 + m16) * 32 + q * 8;
            #pragma unroll
            for (int nt = 0; nt < 12; ++nt) {
                const bf16x8 b = *(const bf16x8*)(wp + (size_t)nt * 16 * 32);
                acc[nt] = __builtin_amdgcn_mfma_f32_16x16x32_bf16(a, b, acc[nt], 0, 0, 0);
            }
        }
    }

    #pragma unroll
    for (int nt = 0; nt < 12; ++nt) {
        const int col = nt * 16 + m16;
        const float bd = bias[col];
        #pragma unroll
        for (int reg = 0; reg < 4; ++reg) {
            const int r = rowbase + q * 4 + reg;
            const int m = r & (L_ - 1);
            const size_t idx = (size_t)r * D_ + col;
            if (IS_CONV1) {
                float v = fmaxf(acc[nt][reg] + bd, 0.f);
                if (m == 0 || m == L_ - 1) v = 0.f;
                outb[idx] = f2b(v);
            } else {
                float v = x2[idx];
                if (m != 0 && m != L_ - 1) v += acc[nt][reg] + bd;
                outf[idx] = v;
            }
        }
    }
}

// ---------------------------------------------------------------------------
extern "C" void kernel_launch(void* const* d_in, const int* in_sizes, int n_in,
                              void* d_out, int out_size, void* d_ws, size_t ws_size,
                              hipStream_t stream)
{
    const float* x    = (const float*)d_in[0];
    const float* ln1g = (const float*)d_in[1];
    const float* ln1b = (const float*)d_in[2];
    const float* wq   = (const float*)d_in[3];
    const float* bq   = (const float*)d_in[4];
    const float* wk   = (const float*)d_in[5];
    const float* bk   = (const float*)d_in[6];
    const float* wv   = (const float*)d_in[7];
    const float* bv   = (const float*)d_in[8];
    const float* wo   = (const float*)d_in[9];
    const float* bo   = (const float*)d_in[10];
    const float* ln2g = (const float*)d_in[11];
    const float* ln2b = (const float*)d_in[12];
    const float* c1w  = (const float*)d_in[13];
    const float* c1b  = (const float*)d_in[14];
    const float* c2w  = (const float*)d_in[15];
    const float* c2b  = (const float*)d_in[16];

    const size_t ROWS = (size_t)16 * L_;            // 32768
    char* ws = (char*)d_ws;
    size_t off = 4096;                               // guard (conv row -1)
    bf16* xn2b = (bf16*)(ws + off); off += ROWS * D_ * 2;    // 12.6 MB
    off += 4096;                                     // guard
    bf16* hpb  = (bf16*)(ws + off); off += ROWS * D_ * 2;    // 12.6 MB
    off += 4096;                                     // guard
    float* x2  = (float*)(ws + off); off += ROWS * D_ * 4;   // 25.2 MB
    bf16* qb   = (bf16*)(ws + off);  off += ROWS * HK_ * 2;  // 3.15 MB
    bf16* kb   = (bf16*)(ws + off);  off += ROWS * HK_ * 2;
    bf16* vb2  = (bf16*)(ws + off);  off += ROWS * HK_ * 2;
    bf16* ctx  = (bf16*)(ws + off);  off += ROWS * HK_ * 2;
    bf16* wrep1 = (bf16*)(ws + off); off += 576 * 192 * 2;   // 221 KB
    bf16* wrep2 = (bf16*)(ws + off); off += 576 * 192 * 2;   // total ~64 MB

    // attention partials ALIAS later-written buffers (consumed by attn_comb
    // before proj_ln2 writes x2 / conv1 writes hpb):
    bf16*  part_o = (bf16*)x2;       // 25.2 MB
    float* part_l = (float*)hpb;     //  4.2 MB

    k_wprep        <<<432, 256, 0, stream>>>(c1w, wrep1);
    k_wprep        <<<432, 256, 0, stream>>>(c2w, wrep2);
    k_ln_qkv       <<<2048, 256, 0, stream>>>(x, ln1g, ln1b, wq, bq, wk, bk, wv, bv, qb, kb, vb2);
    k_attn_part    <<<64 * 36, 128, 0, stream>>>(qb, kb, vb2, part_o, part_l);
    k_attn_comb    <<< 512, 256, 0, stream>>>(part_o, part_l, ctx);
    k_proj_ln2     <<<4096, 192, 0, stream>>>(x, ctx, wo, bo, ln2g, ln2b, x2, xn2b);
    k_conv_mfma<1> <<< 512, 256, 0, stream>>>(xn2b, wrep1, c1b, nullptr, hpb, nullptr);
    k_conv_mfma<0> <<< 512, 256, 0, stream>>>(hpb, wrep2, c2b, x2, nullptr, (float*)d_out);
}